// Round 7
// baseline (54.521 us; speedup 1.0000x reference)
//
#include <hip/hip_runtime.h>
#include <math.h>

#define Bsz 8
#define HWp (512*512)
#define TSX 64
#define TSY 32
#define XR 40          // x-window rows  = TSY+8
#define XC 72          // x-window cols  = TSX+8
#define BR 38          // blur rows
#define BC 70          // blur cols
#define SR 36          // s rows
#define SC 68          // s cols
#define MR 34          // m rows
#define MC 66          // m cols
#define NT 1024
#define K2E 1442.6950408889634f   // 1000*log2(e)
#define T2q 0.17157287525380993f  // tan^2(22.5 deg)

typedef float f2 __attribute__((ext_vector_type(2)));

#if __has_builtin(__builtin_amdgcn_exp2f)
#define EXP2F(x) __builtin_amdgcn_exp2f(x)
#else
#define EXP2F(x) __expf(0.6931471805599453f*(x))
#endif

__device__ __forceinline__ int refl(int i, int n) {
    i = (i < 0) ? -i : i;
    return (i >= n) ? (2*n - 2 - i) : i;
}
__device__ __forceinline__ float ldsUf(float v) {
    return __uint_as_float(__builtin_amdgcn_readfirstlane(__float_as_uint(v)));
}
__device__ __forceinline__ f2 ldsU2(const float* p) {
    f2 v = *(const f2*)p;
    f2 r; r.x = ldsUf(v.x); r.y = ldsUf(v.y);
    return r;
}
__device__ __forceinline__ f2 splat(float v) { f2 r = {v, v}; return r; }

// matsL layout (floats):
//  [0..23] A=Psx@(Pg@We) [o][c]   [24..47] B=Psy@(Pg@We)
//  [48..55] hi*K2E  [56..63] lo*K2E  [64..71] 0.5*wm
//  [72..119] Apk pairs (A[2j][k],A[2j+1][k]) at [(j*3+k)*2]   [120..167] Bpk
//  [144..167 of stage] M1 staging reuses [144..167]? no: M1 staged at [144..167] BEFORE Bpk written?
//  -> M1 staged at [144..167], Bpk written after M1 consumed (same lanes, program order).
__global__ __launch_bounds__(NT, 4) void k_fused(
    const float* __restrict__ x,
    const float* __restrict__ we, const float* __restrict__ pg,
    const float* __restrict__ psx, const float* __restrict__ psy,
    const float* __restrict__ wm, const float* __restrict__ lowt,
    const float* __restrict__ hight,
    float* __restrict__ out, float wc, float wE, float wk)
{
    __shared__ __align__(16) float xw[3*XR*XC];   // A/B: x ; C+: sS(36*68) | mS(34*66)
    __shared__ __align__(16) float blb[3*BR*BC];
    __shared__ __align__(16) float matsL[168];
    __shared__ int anyS;

    const int b  = blockIdx.z;
    const int x0 = blockIdx.x*TSX, y0 = blockIdx.y*TSY;
    const int t  = threadIdx.x;
    const bool inter = (blockIdx.x > 0) && ((int)blockIdx.x < (int)gridDim.x-1) &&
                       (blockIdx.y > 0) && ((int)blockIdx.y < (int)gridDim.y-1);

    if (t == 0) anyS = 0;

    // ---- prologue (wave 0): fold 1x1 mats + thresholds into matsL ----
    if (t < 24) {
        int o = t/3, c = t - o*3;
        float a = 0.f;
        #pragma unroll
        for (int k = 0; k < 8; ++k) a = fmaf(pg[o*8+k], we[k*3+c], a);
        matsL[144 + t] = a;                      // M1 staging
        float av = 0.f, bv = 0.f;
        #pragma unroll
        for (int k = 0; k < 8; ++k) {
            float m1 = matsL[144 + k*3 + c];     // same-wave LDS RAW: ordered
            av = fmaf(psx[o*8+k], m1, av);
            bv = fmaf(psy[o*8+k], m1, bv);
        }
        matsL[t]      = av;
        matsL[24 + t] = bv;
        int pi = ((o>>1)*3 + c)*2 + (o&1);
        matsL[72  + pi] = av;
        matsL[120 + pi] = bv;
    } else if (t < 32) {
        int o = t - 24;
        matsL[48+o] = hight[o] * K2E;
        matsL[56+o] = lowt[o]  * K2E;
        matsL[64+o] = 0.5f * wm[o];
    }

    const float* xb = x + (size_t)b*3*HWp;

    // ---- phase A: x window (reflect) ----
    if (inter) {
        const float* xo = xb + (size_t)(y0-4)*512 + (x0-4);
        for (int i = t; i < 3*XR*18; i += NT) {
            int c = i/720; int j = i - c*720; int r = j/18; int q = j - r*18;
            float4 v = *(const float4*)(xo + (size_t)c*HWp + r*512 + q*4);
            *(float4*)&xw[c*(XR*XC) + r*XC + q*4] = v;
        }
    } else {
        for (int i = t; i < XR*XC; i += NT) {
            int r = i/XC, cc = i - r*XC;
            size_t off = (size_t)refl(y0-4+r,512)*512 + refl(x0-4+cc,512);
            #pragma unroll
            for (int c = 0; c < 3; ++c)
                xw[c*(XR*XC)+i] = xb[(size_t)c*HWp + off];
        }
    }
    __syncthreads();

    // ---- phase B: gaussian blur -> blb ----
    if (inter) {
        if (t < 13*BC) {
            int g = t/BC, cb = t - g*BC, r0 = 3*g;
            #pragma unroll
            for (int c = 0; c < 3; ++c) {
                const float* col = &xw[c*(XR*XC) + cb];
                float* bo = &blb[c*(BR*BC) + cb];
                float a0 = col[r0*XC],     a1 = col[r0*XC+1],     a2 = col[r0*XC+2];
                float e0 = col[(r0+1)*XC], e1 = col[(r0+1)*XC+1], e2 = col[(r0+1)*XC+2];
                #pragma unroll
                for (int ir = 0; ir < 3; ++ir) {
                    int r = r0 + ir;
                    if (r < BR) {
                        float f0 = col[(r+2)*XC], f1 = col[(r+2)*XC+1], f2v = col[(r+2)*XC+2];
                        float t0 = a0+f0, t1 = a1+f1, t2 = a2+f2v;
                        float u = t0+t2, v = e0+e2, w = t1+v;
                        bo[r*BC] = wk*u + wE*w + wc*e1;
                        a0=e0; a1=e1; a2=e2; e0=f0; e1=f1; e2=f2v;
                    }
                }
            }
        }
    } else {
        for (int i = t; i < BR*BC; i += NT) {
            int r = i/BC, cc = i - r*BC;
            int iy = refl(y0-3+r,512) - (y0-4);
            int ix = refl(x0-3+cc,512) - (x0-4);
            const int base = iy*XC + ix;
            #pragma unroll
            for (int c = 0; c < 3; ++c) {
                const float* xp = &xw[c*(XR*XC) + base];
                blb[c*(BR*BC)+i] =
                    wk*(xp[-XC-1]+xp[-XC+1]+xp[XC-1]+xp[XC+1]) +
                    wE*(xp[-XC]+xp[-1]+xp[1]+xp[XC]) + wc*xp[0];
            }
        }
    }
    __syncthreads();

    // ---- phase C: sobel (rolling) -> 8ch mag/octant in regs + s -> sS ----
    f2 mg2[3][4];
    unsigned qk[3];
    const int gC = t/SC, csC = t - gC*SC, r0C = 3*gC;
    const bool actC = (t < 12*SC);
    if (actC) {
        // uniform consts -> SGPRs
        f2 A2[12], B2[12];
        #pragma unroll
        for (int j = 0; j < 12; ++j) {
            A2[j] = ldsU2(matsL + 72  + 2*j);
            B2[j] = ldsU2(matsL + 120 + 2*j);
        }
        // rolling per-channel sobel state
        float D0[3], D1[3], E0[3], E1[3];
        #pragma unroll
        for (int c = 0; c < 3; ++c) {
            const float* blc = &blb[c*(BR*BC) + csC];
            float p0 = blc[r0C*BC],     p1 = blc[r0C*BC+1],     p2 = blc[r0C*BC+2];
            float q0 = blc[(r0C+1)*BC], q1 = blc[(r0C+1)*BC+1], q2 = blc[(r0C+1)*BC+2];
            D0[c] = p2-p0; E0[c] = fmaf(0.5f, p0+p2, p1);
            D1[c] = q2-q0; E1[c] = fmaf(0.5f, q0+q2, q1);
        }
        const f2 eps2 = {1e-10f, 1e-10f};
        #pragma unroll
        for (int ir = 0; ir < 3; ++ir) {
            float txv[3], tyv[3];
            #pragma unroll
            for (int c = 0; c < 3; ++c) {
                const float* wr = &blb[c*(BR*BC) + (r0C+2+ir)*BC + csC];
                float w0 = wr[0], w1 = wr[1], w2 = wr[2];
                float D2 = w2-w0, E2 = fmaf(0.5f, w0+w2, w1);
                txv[c] = fmaf(0.5f, D0[c]+D2, D1[c]);
                tyv[c] = E2 - E0[c];
                D0[c] = D1[c]; D1[c] = D2; E0[c] = E1[c]; E1[c] = E2;
            }
            f2 s2 = {0.f, 0.f};
            unsigned pk = 0;
            #pragma unroll
            for (int j = 0; j < 4; ++j) {
                f2 gx = __builtin_elementwise_fma(A2[j*3+0], splat(txv[0]),
                        __builtin_elementwise_fma(A2[j*3+1], splat(txv[1]),
                                                  A2[j*3+2]*splat(txv[2])));
                f2 gy = __builtin_elementwise_fma(B2[j*3+0], splat(tyv[0]),
                        __builtin_elementwise_fma(B2[j*3+1], splat(tyv[1]),
                                                  B2[j*3+2]*splat(tyv[2])));
                f2 gx2 = gx*gx, gy2 = gy*gy;
                f2 r2 = gx2 + gy2 + eps2;
                f2 m; m.x = __builtin_amdgcn_sqrtf(r2.x);
                      m.y = __builtin_amdgcn_sqrtf(r2.y);
                mg2[ir][j] = m;
                s2 += m;
                unsigned d0 = 1u | (((__float_as_uint(gx.x) ^ __float_as_uint(gy.x)) >> 30) & 2u);
                unsigned q0 = (gx2.x <= T2q*gy2.x) ? 2u : d0;
                q0 = (gy2.x <= T2q*gx2.x) ? 0u : q0;
                unsigned d1 = 1u | (((__float_as_uint(gx.y) ^ __float_as_uint(gy.y)) >> 30) & 2u);
                unsigned q1 = (gx2.y <= T2q*gy2.y) ? 2u : d1;
                q1 = (gy2.y <= T2q*gx2.y) ? 0u : q1;
                pk |= (q0 << (4*j)) | (q1 << (4*j+2));
            }
            qk[ir] = pk;
            #pragma unroll
            for (int j = 0; j < 4; ++j) { asm volatile("" : "+v"(mg2[ir][j])); }
            asm volatile("" : "+v"(qk[ir]));
            int rr = r0C + ir;
            int gy_ = y0-2+rr, gx_ = x0-2+csC;
            bool inimg = ((unsigned)gy_ < 512u) && ((unsigned)gx_ < 512u);
            xw[rr*SC + csC] = inimg ? (s2.x + s2.y) : 0.f;   // sS (x window dead)
        }
    }
    __syncthreads();

    // ---- phase D: NMS + soft double threshold + merge -> mS ----
    bool anyL = false;
    {
        const float* sS = xw;
        float* mS = xw + SR*SC;
        if (actC && csC >= 1 && csC <= MC) {
            f2 hiK2[4], loK2[4], wm2[4];
            #pragma unroll
            for (int j = 0; j < 4; ++j) {
                hiK2[j] = ldsU2(matsL + 48 + 2*j);
                loK2[j] = ldsU2(matsL + 56 + 2*j);
                wm2[j]  = ldsU2(matsL + 64 + 2*j);
            }
            int ra = r0C-1 < 0 ? 0 : r0C-1;
            const float* pa = &sS[ra*SC + csC];
            const float* pb = &sS[r0C*SC + csC];
            const float* pc = &sS[(r0C+1)*SC + csC];
            float l0=pa[-1], c0=pa[0], r0v=pa[1];
            float l1=pb[-1], c1=pb[0], r1v=pb[1];
            float l2=pc[-1], c2=pc[0], r2v=pc[1];
            const f2 nK2E = {-K2E, -K2E};
            #pragma unroll
            for (int ir = 0; ir < 3; ++ir) {
                int r = r0C + ir;
                if (r >= 1 && r <= MR) {
                    float sc = c1;
                    unsigned mask = 0;
                    mask |= ((sc > r1v) && (sc > l1)) ? 1u : 0u;  // E/W
                    mask |= ((sc > r2v) && (sc > l0)) ? 2u : 0u;  // SE/NW
                    mask |= ((sc > c2)  && (sc > c0)) ? 4u : 0u;  // S/N
                    mask |= ((sc > l2)  && (sc > r0v)) ? 8u : 0u; // SW/NE
                    unsigned pk = qk[ir];
                    f2 acc = {0.f, 0.f};
                    #pragma unroll
                    for (int j = 0; j < 4; ++j) {
                        unsigned ii = pk >> (4*j);
                        f2 nms;
                        nms.x = ((mask >> (ii & 3u)) & 1u)      ? mg2[ir][j].x : 0.f;
                        nms.y = ((mask >> ((ii>>2) & 3u)) & 1u) ? mg2[ir][j].y : 0.f;
                        f2 aH = __builtin_elementwise_fma(nms, nK2E, hiK2[j]);
                        f2 aL = __builtin_elementwise_fma(nms, nK2E, loK2[j]);
                        f2 sh; sh.x = __builtin_amdgcn_rcpf(1.f + EXP2F(aH.x));
                               sh.y = __builtin_amdgcn_rcpf(1.f + EXP2F(aH.y));
                        f2 sl; sl.x = __builtin_amdgcn_rcpf(1.f + EXP2F(aL.x));
                               sl.y = __builtin_amdgcn_rcpf(1.f + EXP2F(aL.y));
                        acc = __builtin_elementwise_fma(wm2[j], sh + sl, acc);
                    }
                    float m = acc.x + acc.y;
                    mS[(r-1)*MC + (csC-1)] = m;
                    anyL |= (m == 1.0f);
                }
                if (ir < 2) {
                    int rn = r0C + 2 + ir; rn = rn > SR-1 ? SR-1 : rn;
                    const float* pn = &sS[rn*SC + csC];
                    l0=l1; c0=c1; r0v=r1v;
                    l1=l2; c1=c2; r1v=r2v;
                    l2=pn[-1]; c2=pn[0]; r2v=pn[1];
                }
            }
        }
    }
    if (anyL) anyS = 1;
    __syncthreads();

    // ---- phase E: one-step hysteresis (reflect) -> out; vector-zero fast path ----
    {
        const float* mS = xw + SR*SC;
        float* op = out + (size_t)b*HWp;
        if (anyS == 0) {
            if (t < 512) {
                int row = t >> 4, q = t & 15;
                float4 z = {0.f, 0.f, 0.f, 0.f};
                *(float4*)(op + (size_t)(y0+row)*512 + x0 + q*4) = z;
            }
        } else {
            for (int i2 = t; i2 < TSY*TSX; i2 += NT) {
                int ty_ = i2>>6, tx_ = i2&63;
                int y = y0 + ty_, xg = x0 + tx_;
                const float* mp = &mS[(ty_+1)*MC + (tx_+1)];
                float mc = mp[0];
                float hy = 0.f;
                if (inter) {
                    #pragma unroll
                    for (int dy = -1; dy <= 1; ++dy)
                        #pragma unroll
                        for (int dx = -1; dx <= 1; ++dx)
                            hy += (mp[dy*MC+dx] == 1.0f) ? 1.25f : 0.f;
                } else {
                    #pragma unroll
                    for (int dy = -1; dy <= 1; ++dy)
                        #pragma unroll
                        for (int dx = -1; dx <= 1; ++dx) {
                            int ly = refl(y+dy,512) - (y0-1);
                            int lx = refl(xg+dx,512) - (x0-1);
                            hy += (mS[ly*MC+lx] == 1.0f) ? 1.25f : 0.f;
                        }
                }
                float strong = (mc == 1.0f) ? mc : 0.f;
                op[(size_t)y*512 + xg] =
                    (((hy > 1.0f) && (mc == 0.5f)) ? mc : 0.f) + strong;
            }
        }
    }
}

extern "C" void kernel_launch(void* const* d_in, const int* in_sizes, int n_in,
                              void* d_out, int out_size, void* d_ws, size_t ws_size,
                              hipStream_t stream) {
    const float* x    = (const float*)d_in[0];
    const float* we   = (const float*)d_in[1];
    const float* pg   = (const float*)d_in[2];
    const float* psx  = (const float*)d_in[3];
    const float* psy  = (const float*)d_in[4];
    const float* wm   = (const float*)d_in[5];
    const float* lowt = (const float*)d_in[6];
    const float* hit  = (const float*)d_in[7];
    float* outp = (float*)d_out;

    // gaussian 3x3 (sigma=3), normalized (double, like numpy)
    double e1 = exp(-1.0/18.0), e2 = exp(-2.0/18.0);
    double sum = 1.0 + 4.0*e1 + 4.0*e2;
    float wc = (float)(1.0/sum), wE = (float)(e1/sum), wk = (float)(e2/sum);

    k_fused<<<dim3(512/TSX, 512/TSY, Bsz), dim3(NT), 0, stream>>>(
        x, we, pg, psx, psy, wm, lowt, hit, outp, wc, wE, wk);
}

// Round 8
// 46.237 us; speedup vs baseline: 1.1792x; 1.1792x over previous
//
#include <hip/hip_runtime.h>
#include <math.h>

#define Bsz 8
#define HWp (512*512)
#define TS 32
#define SG 36          // s-grid (out + halo 2)
#define MG 34          // m-grid (out + halo 1)
#define XW 40          // x window (out + halo 4)
#define BW 38          // blur window (out + halo 3)
#define NT 512
#define K2E 1442.6950408889634f   // 1000*log2(e)
#define T2q 0.17157287525380993f  // tan^2(22.5 deg)

typedef float f2 __attribute__((ext_vector_type(2)));

#if __has_builtin(__builtin_amdgcn_exp2f)
#define EXP2F(x) __builtin_amdgcn_exp2f(x)
#else
#define EXP2F(x) __expf(0.6931471805599453f*(x))
#endif

__device__ __forceinline__ int refl(int i, int n) {
    i = (i < 0) ? -i : i;
    return (i >= n) ? (2*n - 2 - i) : i;
}
__device__ __forceinline__ float ldsUf(float v) {
    return __uint_as_float(__builtin_amdgcn_readfirstlane(__float_as_uint(v)));
}
__device__ __forceinline__ f2 ldsU2(const float* p) {
    f2 v = *(const f2*)p;
    f2 r; r.x = ldsUf(v.x); r.y = ldsUf(v.y);
    return r;
}

// matsL layout (floats):
//  [0..23]  Apk pairs (A[2j][k],A[2j+1][k]) at [(j*3+k)*2], A=Psx@(Pg@We)
//  [24..47] Bpk pairs, B=Psy@(Pg@We)
//  [48..55] midK = K2E*(hi+lo)/2   [56..63] PH = 2^{K2E*(hi-lo)/2}
//  [64..71] PL = 2^{-K2E*(hi-lo)/2} [72..79] wmh = 0.5*wm
//  [80..103] M1 staging (Pg@We), consumed same-wave in prologue
__global__ __launch_bounds__(NT) void k_fused(
    const float* __restrict__ x,
    const float* __restrict__ we, const float* __restrict__ pg,
    const float* __restrict__ psx, const float* __restrict__ psy,
    const float* __restrict__ wm, const float* __restrict__ lowt,
    const float* __restrict__ hight,
    float* __restrict__ out, float wc, float wE, float wk)
{
    __shared__ float sm1[3*XW*XW];   // A/B: x window ; C+: sS(1296) | mS(1156)
    __shared__ float blb[3*BW*BW];
    __shared__ __align__(16) float matsL[104];
    __shared__ int anyS;

    const int b  = blockIdx.z;
    const int x0 = blockIdx.x*TS, y0 = blockIdx.y*TS;
    const int t  = threadIdx.x;
    const bool inter = (blockIdx.x > 0) && ((int)blockIdx.x < (int)gridDim.x-1) &&
                       (blockIdx.y > 0) && ((int)blockIdx.y < (int)gridDim.y-1);

    if (t == 0) anyS = 0;

    // ---- prologue (wave 0 lanes 0..31): fold mats + thresholds into matsL ----
    if (t < 24) {
        int o = t/3, c = t - o*3;
        float a = 0.f;
        #pragma unroll
        for (int k = 0; k < 8; ++k) a = fmaf(pg[o*8+k], we[k*3+c], a);
        matsL[80 + t] = a;                       // M1 staging
        float av = 0.f, bv = 0.f;
        #pragma unroll
        for (int k = 0; k < 8; ++k) {
            float m1 = matsL[80 + k*3 + c];      // same-wave LDS RAW: lockstep-ordered
            av = fmaf(psx[o*8+k], m1, av);
            bv = fmaf(psy[o*8+k], m1, bv);
        }
        int pi = ((o>>1)*3 + c)*2 + (o&1);
        matsL[pi]      = av;
        matsL[24 + pi] = bv;
    } else if (t < 32) {
        int o = t - 24;
        float hi = hight[o], lo = lowt[o];
        float d = K2E * 0.5f * (hi - lo);
        matsL[48+o] = K2E * 0.5f * (hi + lo);    // midK
        matsL[56+o] = exp2f(d);                  // PH
        matsL[64+o] = exp2f(-d);                 // PL
        matsL[72+o] = 0.5f * wm[o];              // wmh
    }

    const float* xb = x + (size_t)b*3*HWp;

    // ---- phase A: x window (reflect) -> sm1 ----
    if (inter) {
        const float* xo = xb + (size_t)(y0-4)*512 + (x0-4);
        for (int i = t; i < 3*XW*10; i += NT) {
            int c = i/400; int j = i - c*400; int r = j/10; int q = j - r*10;
            float4 v = *(const float4*)(xo + (size_t)c*HWp + r*512 + q*4);
            *(float4*)&sm1[c*(XW*XW) + r*XW + q*4] = v;
        }
    } else {
        for (int i = t; i < XW*XW; i += NT) {
            int r = i/XW, cc = i - r*XW;
            size_t off = (size_t)refl(y0-4+r,512)*512 + refl(x0-4+cc,512);
            #pragma unroll
            for (int c = 0; c < 3; ++c)
                sm1[c*(XW*XW)+i] = xb[(size_t)c*HWp + off];
        }
    }
    __syncthreads();

    // ---- phase B: gaussian blur -> blb ----
    if (inter) {
        if (t < 494) {
            int g = t/38, cb = t - g*38, r0 = 3*g;
            #pragma unroll
            for (int c = 0; c < 3; ++c) {
                const float* col = &sm1[c*(XW*XW) + cb];
                float* bo = &blb[c*(BW*BW) + cb];
                float a0 = col[r0*XW],     a1 = col[r0*XW+1],     a2 = col[r0*XW+2];
                float e0 = col[(r0+1)*XW], e1 = col[(r0+1)*XW+1], e2 = col[(r0+1)*XW+2];
                #pragma unroll
                for (int ir = 0; ir < 3; ++ir) {
                    int r = r0 + ir;
                    if (r < BW) {
                        float f0 = col[(r+2)*XW], f1 = col[(r+2)*XW+1], f2v = col[(r+2)*XW+2];
                        float t0 = a0+f0, t1 = a1+f1, t2 = a2+f2v;
                        float u = t0+t2, v = e0+e2, w = t1+v;
                        bo[r*BW] = wk*u + wE*w + wc*e1;
                        a0=e0; a1=e1; a2=e2; e0=f0; e1=f1; e2=f2v;
                    }
                }
            }
        }
    } else {
        for (int i = t; i < BW*BW; i += NT) {
            int r = i/BW, cc = i - r*BW;
            int iy = refl(y0-3+r,512) - (y0-4);
            int ix = refl(x0-3+cc,512) - (x0-4);
            const int base = iy*XW + ix;
            #pragma unroll
            for (int c = 0; c < 3; ++c) {
                const float* xp = &sm1[c*(XW*XW) + base];
                blb[c*(BW*BW)+i] =
                    wk*(xp[-XW-1]+xp[-XW+1]+xp[XW-1]+xp[XW+1]) +
                    wE*(xp[-XW]+xp[-1]+xp[1]+xp[XW]) + wc*xp[0];
            }
        }
    }
    __syncthreads();

    // ---- phase C: sobel via rolling regs -> mag/octant (regs, pinned) + s -> sS ----
    f2 mg2[3][4];
    unsigned qk[3];
    const int gC = t/36, csC = t - gC*36, r0C = 3*gC;
    const bool actC = (t < 432);
    if (actC) {
        f2 A2[12], B2[12];
        #pragma unroll
        for (int j = 0; j < 12; ++j) {
            A2[j] = ldsU2(matsL + 2*j);
            B2[j] = ldsU2(matsL + 24 + 2*j);
        }
        float D0[3], D1[3], E0[3], E1[3];
        #pragma unroll
        for (int c = 0; c < 3; ++c) {
            const float* blc = &blb[c*(BW*BW) + csC];
            float p0 = blc[r0C*BW],     p1 = blc[r0C*BW+1],     p2 = blc[r0C*BW+2];
            float q0 = blc[(r0C+1)*BW], q1 = blc[(r0C+1)*BW+1], q2 = blc[(r0C+1)*BW+2];
            D0[c] = p2-p0; E0[c] = fmaf(0.5f, p0+p2, p1);
            D1[c] = q2-q0; E1[c] = fmaf(0.5f, q0+q2, q1);
        }
        #pragma unroll
        for (int ir = 0; ir < 3; ++ir) {
            float txv[3], tyv[3];
            #pragma unroll
            for (int c = 0; c < 3; ++c) {
                const float* wr = &blb[c*(BW*BW) + (r0C+2+ir)*BW + csC];
                float w0 = wr[0], w1 = wr[1], w2 = wr[2];
                float D2 = w2-w0, E2 = fmaf(0.5f, w0+w2, w1);
                txv[c] = fmaf(0.5f, D0[c]+D2, D1[c]);
                tyv[c] = E2 - E0[c];
                D0[c] = D1[c]; D1[c] = D2; E0[c] = E1[c]; E1[c] = E2;
            }
            float s = 0.f;
            unsigned pk = 0;
            #pragma unroll
            for (int j = 0; j < 4; ++j) {
                float gxa = fmaf(A2[j*3].x, txv[0], fmaf(A2[j*3+1].x, txv[1], A2[j*3+2].x*txv[2]));
                float gxb = fmaf(A2[j*3].y, txv[0], fmaf(A2[j*3+1].y, txv[1], A2[j*3+2].y*txv[2]));
                float gya = fmaf(B2[j*3].x, tyv[0], fmaf(B2[j*3+1].x, tyv[1], B2[j*3+2].x*tyv[2]));
                float gyb = fmaf(B2[j*3].y, tyv[0], fmaf(B2[j*3+1].y, tyv[1], B2[j*3+2].y*tyv[2]));
                float gx2a = gxa*gxa, gy2a = gya*gya;
                float gx2b = gxb*gxb, gy2b = gyb*gyb;
                f2 m;
                m.x = __builtin_amdgcn_sqrtf(gx2a + gy2a + 1e-10f);
                m.y = __builtin_amdgcn_sqrtf(gx2b + gy2b + 1e-10f);
                mg2[ir][j] = m;
                s += m.x + m.y;
                unsigned d0 = 1u | (((__float_as_uint(gxa) ^ __float_as_uint(gya)) >> 30) & 2u);
                unsigned q0 = (gx2a <= T2q*gy2a) ? 2u : d0;
                q0 = (gy2a <= T2q*gx2a) ? 0u : q0;
                unsigned d1 = 1u | (((__float_as_uint(gxb) ^ __float_as_uint(gyb)) >> 30) & 2u);
                unsigned q1 = (gx2b <= T2q*gy2b) ? 2u : d1;
                q1 = (gy2b <= T2q*gx2b) ? 0u : q1;
                pk |= (q0 << (4*j)) | (q1 << (4*j+2));
            }
            qk[ir] = pk;
            #pragma unroll
            for (int j = 0; j < 4; ++j) { asm volatile("" : "+v"(mg2[ir][j])); }
            asm volatile("" : "+v"(qk[ir]));
            int rr = r0C + ir;
            int gy_ = y0-2+rr, gx_ = x0-2+csC;
            bool inimg = ((unsigned)gy_ < 512u) && ((unsigned)gx_ < 512u);
            sm1[rr*SG + csC] = inimg ? s : 0.f;   // sS (x window dead)
        }
    }
    __syncthreads();

    // ---- phase D: NMS + single-exp2 double-sigmoid + merge -> mS ----
    bool anyL = false;
    {
        const float* sS = sm1;
        float* mS = sm1 + SG*SG;
        if (actC && csC >= 1 && csC <= 34) {
            f2 mid2[4], ph2[4], pl2[4], wm2[4];
            #pragma unroll
            for (int j = 0; j < 4; ++j) {
                mid2[j] = ldsU2(matsL + 48 + 2*j);
                ph2[j]  = ldsU2(matsL + 56 + 2*j);
                pl2[j]  = ldsU2(matsL + 64 + 2*j);
                wm2[j]  = ldsU2(matsL + 72 + 2*j);
            }
            int ra = r0C-1 < 0 ? 0 : r0C-1;
            const float* pa = &sS[ra*SG + csC];
            const float* pb = &sS[r0C*SG + csC];
            const float* pc = &sS[(r0C+1)*SG + csC];
            float l0=pa[-1], c0=pa[0], r0v=pa[1];
            float l1=pb[-1], c1=pb[0], r1v=pb[1];
            float l2=pc[-1], c2=pc[0], r2v=pc[1];
            #pragma unroll
            for (int ir = 0; ir < 3; ++ir) {
                int r = r0C + ir;
                if (r >= 1 && r <= 34) {
                    float sc = c1;
                    unsigned mask = 0;
                    mask |= ((sc > r1v) && (sc > l1)) ? 1u : 0u;  // E/W
                    mask |= ((sc > r2v) && (sc > l0)) ? 2u : 0u;  // SE/NW
                    mask |= ((sc > c2)  && (sc > c0)) ? 4u : 0u;  // S/N
                    mask |= ((sc > l2)  && (sc > r0v)) ? 8u : 0u; // SW/NE
                    unsigned pk = qk[ir];
                    float m = 0.f;
                    #pragma unroll
                    for (int j = 0; j < 4; ++j) {
                        unsigned ii = pk >> (4*j);
                        float n0 = ((mask >> (ii & 3u)) & 1u)      ? mg2[ir][j].x : 0.f;
                        float n1 = ((mask >> ((ii>>2) & 3u)) & 1u) ? mg2[ir][j].y : 0.f;
                        // one exp2 per channel: e = 2^(midK - K*nms); sig_hi=1/(1+e*PH), sig_lo=1/(1+e*PL)
                        float e0 = EXP2F(fmaf(n0, -K2E, mid2[j].x));
                        float e1 = EXP2F(fmaf(n1, -K2E, mid2[j].y));
                        float sh0 = __builtin_amdgcn_rcpf(fmaf(e0, ph2[j].x, 1.f));
                        float sl0 = __builtin_amdgcn_rcpf(fmaf(e0, pl2[j].x, 1.f));
                        float sh1 = __builtin_amdgcn_rcpf(fmaf(e1, ph2[j].y, 1.f));
                        float sl1 = __builtin_amdgcn_rcpf(fmaf(e1, pl2[j].y, 1.f));
                        m = fmaf(wm2[j].x, sh0 + sl0, m);
                        m = fmaf(wm2[j].y, sh1 + sl1, m);
                    }
                    mS[(r-1)*MG + (csC-1)] = m;
                    anyL |= (m == 1.0f);
                }
                if (ir < 2) {
                    int rn = r0C + 2 + ir; rn = rn > 35 ? 35 : rn;
                    const float* pn = &sS[rn*SG + csC];
                    l0=l1; c0=c1; r0v=r1v;
                    l1=l2; c1=c2; r1v=r2v;
                    l2=pn[-1]; c2=pn[0]; r2v=pn[1];
                }
            }
        }
    }
    if (anyL) anyS = 1;
    __syncthreads();

    // ---- phase E: one-step hysteresis (reflect) -> out; vector-zero fast path ----
    {
        const float* mS = sm1 + SG*SG;
        float* op = out + (size_t)b*HWp;
        if (anyS == 0) {
            if (t < 256) {
                int row = t >> 3, q = t & 7;
                float4 z = {0.f, 0.f, 0.f, 0.f};
                *(float4*)(op + (size_t)(y0+row)*512 + x0 + q*4) = z;
            }
        } else {
            for (int i2 = t; i2 < TS*TS; i2 += NT) {
                int ty_ = i2>>5, tx_ = i2&31;
                int y = y0 + ty_, xg = x0 + tx_;
                const float* mp = &mS[(ty_+1)*MG + (tx_+1)];
                float mc = mp[0];
                float hy = 0.f;
                if (inter) {
                    #pragma unroll
                    for (int dy = -1; dy <= 1; ++dy)
                        #pragma unroll
                        for (int dx = -1; dx <= 1; ++dx)
                            hy += (mp[dy*MG+dx] == 1.0f) ? 1.25f : 0.f;
                } else {
                    #pragma unroll
                    for (int dy = -1; dy <= 1; ++dy)
                        #pragma unroll
                        for (int dx = -1; dx <= 1; ++dx) {
                            int ly = refl(y+dy,512) - (y0-1);
                            int lx = refl(xg+dx,512) - (x0-1);
                            hy += (mS[ly*MG+lx] == 1.0f) ? 1.25f : 0.f;
                        }
                }
                float strong = (mc == 1.0f) ? mc : 0.f;
                op[(size_t)y*512 + xg] =
                    (((hy > 1.0f) && (mc == 0.5f)) ? mc : 0.f) + strong;
            }
        }
    }
}

extern "C" void kernel_launch(void* const* d_in, const int* in_sizes, int n_in,
                              void* d_out, int out_size, void* d_ws, size_t ws_size,
                              hipStream_t stream) {
    const float* x    = (const float*)d_in[0];
    const float* we   = (const float*)d_in[1];
    const float* pg   = (const float*)d_in[2];
    const float* psx  = (const float*)d_in[3];
    const float* psy  = (const float*)d_in[4];
    const float* wm   = (const float*)d_in[5];
    const float* lowt = (const float*)d_in[6];
    const float* hit  = (const float*)d_in[7];
    float* outp = (float*)d_out;

    // gaussian 3x3 (sigma=3), normalized (double, like numpy)
    double e1 = exp(-1.0/18.0), e2 = exp(-2.0/18.0);
    double sum = 1.0 + 4.0*e1 + 4.0*e2;
    float wc = (float)(1.0/sum), wE = (float)(e1/sum), wk = (float)(e2/sum);

    k_fused<<<dim3(512/TS, 512/TS, Bsz), dim3(NT), 0, stream>>>(
        x, we, pg, psx, psy, wm, lowt, hit, outp, wc, wE, wk);
}